// Round 1
// baseline (3152.881 us; speedup 1.0000x reference)
//
#include <hip/hip_runtime.h>
#include <hip/hip_bf16.h>
#include <math.h>

#define DD 64
#define HH 128

__device__ __forceinline__ float elu1(float x) {
    return x > 0.0f ? x : (expf(x) - 1.0f);
}

__global__ __launch_bounds__(256) void deg_kernel(
    const int* __restrict__ dst1, const int* __restrict__ dst2,
    float* __restrict__ deg1, float* __restrict__ deg2, int E) {
    int e = blockIdx.x * blockDim.x + threadIdx.x;
    if (e < E) {
        atomicAdd(&deg1[dst1[e]], 1.0f);
        atomicAdd(&deg2[dst2[e]], 1.0f);
    }
}

// one wave per edge; lane = feature index. Coalesced 256B gather + 64-lane atomicAdd.
__global__ __launch_bounds__(256) void scatter_kernel(
    const float* __restrict__ h,
    const int* __restrict__ src1, const int* __restrict__ dst1,
    const int* __restrict__ src2, const int* __restrict__ dst2,
    float* __restrict__ agg1, float* __restrict__ agg2, int E) {
    int wave = blockIdx.x * 4 + (threadIdx.x >> 6);
    int lane = threadIdx.x & 63;
    if (wave < E) {
        int s = src1[wave];
        int d = dst1[wave];
        float v = h[(size_t)s * DD + lane];
        atomicAdd(&agg1[(size_t)d * DD + lane], v);
    } else if (wave < 2 * E) {
        int e = wave - E;
        int s = src2[e];
        int d = dst2[e];
        float v = h[(size_t)s * DD + lane];
        atomicAdd(&agg2[(size_t)d * DD + lane], v);
    }
}

// wave-per-node fused: ident/e1/e2 matvecs + ELU + semantic-attention projections.
// e1 -> agg1 in place, e2 -> agg2 in place; w partial sums -> w_acc via atomics.
__global__ __launch_bounds__(256) void fuse_kernel(
    const float* __restrict__ h,
    const float* __restrict__ W_id, const float* __restrict__ b_id,
    const float* __restrict__ W1, const float* __restrict__ b1,
    const float* __restrict__ W2, const float* __restrict__ b2,
    const float* __restrict__ Wp1, const float* __restrict__ bp1,
    const float* __restrict__ Wp2,
    const float* __restrict__ deg1, const float* __restrict__ deg2,
    float* __restrict__ agg1, float* __restrict__ agg2,
    float* __restrict__ w_acc, int N)
{
    __shared__ float sW[3 * DD * DD];          // 48 KB: [W_id | W1 | W2]
    __shared__ __hip_bfloat16 sWp1[DD * HH];   // 16 KB
    for (int i = threadIdx.x; i < 3 * DD * DD; i += blockDim.x) {
        float v;
        if (i < DD * DD)            v = W_id[i];
        else if (i < 2 * DD * DD)   v = W1[i - DD * DD];
        else                        v = W2[i - 2 * DD * DD];
        sW[i] = v;
    }
    for (int i = threadIdx.x; i < DD * HH; i += blockDim.x)
        sWp1[i] = __float2bfloat16(Wp1[i]);

    int lane = threadIdx.x & 63;
    float bb_id  = b_id[lane];
    float bb1    = b1[lane];
    float bb2    = b2[lane];
    float bp_lo  = bp1[lane];
    float bp_hi  = bp1[lane + 64];
    float wp2_lo = Wp2[lane];
    float wp2_hi = Wp2[lane + 64];
    __syncthreads();

    int wave   = blockIdx.x * 4 + (threadIdx.x >> 6);
    int nwaves = gridDim.x * 4;
    float wpart0 = 0.f, wpart1 = 0.f, wpart2 = 0.f;

    for (int n = wave; n < N; n += nwaves) {
        size_t base = (size_t)n * DD;
        float hv = h[base + lane];
        float d1 = deg1[n]; float inv1 = d1 > 0.f ? 1.0f / d1 : 0.f;
        float d2 = deg2[n]; float inv2 = d2 > 0.f ? 1.0f / d2 : 0.f;
        float a1 = agg1[base + lane] * inv1;
        float a2 = agg2[base + lane] * inv2;

        float acc0 = bb_id, acc1 = bb1, acc2 = bb2;
        #pragma unroll
        for (int k = 0; k < DD; k++) {
            float w0 = sW[k * DD + lane];
            float w1 = sW[DD * DD + k * DD + lane];
            float w2 = sW[2 * DD * DD + k * DD + lane];
            acc0 += __shfl(hv, k, 64) * w0;
            acc1 += __shfl(a1, k, 64) * w1;
            acc2 += __shfl(a2, k, 64) * w2;
        }
        float z0 = acc0;
        float z1 = elu1(acc1);
        float z2 = elu1(acc2);
        agg1[base + lane] = z1;
        agg2[base + lane] = z2;

        // semantic-attention projections: lane j owns columns j and j+64 of H=128
        float t0a = bp_lo, t0b = bp_hi;
        float t1a = bp_lo, t1b = bp_hi;
        float t2a = bp_lo, t2b = bp_hi;
        #pragma unroll
        for (int k = 0; k < DD; k++) {
            float wlo = __bfloat162float(sWp1[k * HH + lane]);
            float whi = __bfloat162float(sWp1[k * HH + 64 + lane]);
            float z0k = __shfl(z0, k, 64);
            float z1k = __shfl(z1, k, 64);
            float z2k = __shfl(z2, k, 64);
            t0a += z0k * wlo; t0b += z0k * whi;
            t1a += z1k * wlo; t1b += z1k * whi;
            t2a += z2k * wlo; t2b += z2k * whi;
        }
        // per-lane partial of tanh(t) @ Wp2 (wave-sum deferred to the end)
        wpart0 += tanhf(t0a) * wp2_lo + tanhf(t0b) * wp2_hi;
        wpart1 += tanhf(t1a) * wp2_lo + tanhf(t1b) * wp2_hi;
        wpart2 += tanhf(t2a) * wp2_lo + tanhf(t2b) * wp2_hi;
    }

    #pragma unroll
    for (int off = 32; off >= 1; off >>= 1) {
        wpart0 += __shfl_xor(wpart0, off, 64);
        wpart1 += __shfl_xor(wpart1, off, 64);
        wpart2 += __shfl_xor(wpart2, off, 64);
    }
    if (lane == 0) {
        atomicAdd(&w_acc[0], wpart0);
        atomicAdd(&w_acc[1], wpart1);
        atomicAdd(&w_acc[2], wpart2);
    }
}

__global__ __launch_bounds__(256) void out_kernel(
    const float* __restrict__ h,
    const float* __restrict__ W_id, const float* __restrict__ b_id,
    const float* __restrict__ agg1, const float* __restrict__ agg2,
    const float* __restrict__ w_acc,
    float* __restrict__ out, int N, float invN)
{
    __shared__ float sW[DD * DD];
    for (int i = threadIdx.x; i < DD * DD; i += blockDim.x) sW[i] = W_id[i];
    int lane = threadIdx.x & 63;
    float bb = b_id[lane];
    float w0 = w_acc[0] * invN;
    float w1 = w_acc[1] * invN;
    float w2 = w_acc[2] * invN;
    __syncthreads();

    float m  = fmaxf(w0, fmaxf(w1, w2));
    float e0 = expf(w0 - m), e1 = expf(w1 - m), e2 = expf(w2 - m);
    float s  = 1.0f / (e0 + e1 + e2);
    float beta0 = e0 * s, beta1 = e1 * s, beta2 = e2 * s;

    int wave   = blockIdx.x * 4 + (threadIdx.x >> 6);
    int nwaves = gridDim.x * 4;
    for (int n = wave; n < N; n += nwaves) {
        size_t base = (size_t)n * DD;
        float hv = h[base + lane];
        float acc = bb;
        #pragma unroll
        for (int k = 0; k < DD; k++)
            acc += __shfl(hv, k, 64) * sW[k * DD + lane];
        out[base + lane] = beta0 * acc + beta1 * agg1[base + lane] + beta2 * agg2[base + lane];
    }
}

extern "C" void kernel_launch(void* const* d_in, const int* in_sizes, int n_in,
                              void* d_out, int out_size, void* d_ws, size_t ws_size,
                              hipStream_t stream) {
    const float* h    = (const float*)d_in[0];
    const int*   src1 = (const int*)d_in[1];
    const int*   dst1 = (const int*)d_in[2];
    const int*   src2 = (const int*)d_in[3];
    const int*   dst2 = (const int*)d_in[4];
    const float* W_id = (const float*)d_in[5];
    const float* b_id = (const float*)d_in[6];
    const float* W1   = (const float*)d_in[7];
    const float* b1   = (const float*)d_in[8];
    const float* W2   = (const float*)d_in[9];
    const float* b2   = (const float*)d_in[10];
    const float* Wp1  = (const float*)d_in[11];
    const float* bp1  = (const float*)d_in[12];
    const float* Wp2  = (const float*)d_in[13];
    float* out = (float*)d_out;

    int N = in_sizes[0] / DD;
    int E = in_sizes[1];

    float* ws    = (float*)d_ws;
    float* agg1  = ws;
    float* agg2  = agg1 + (size_t)N * DD;
    float* deg1  = agg2 + (size_t)N * DD;
    float* deg2  = deg1 + N;
    float* w_acc = deg2 + N;

    size_t zero_bytes = ((size_t)2 * N * DD + 2 * (size_t)N + 8) * sizeof(float);
    hipMemsetAsync(d_ws, 0, zero_bytes, stream);

    deg_kernel<<<(E + 255) / 256, 256, 0, stream>>>(dst1, dst2, deg1, deg2, E);

    int swaves = 2 * E;
    scatter_kernel<<<(swaves + 3) / 4, 256, 0, stream>>>(h, src1, dst1, src2, dst2, agg1, agg2, E);

    fuse_kernel<<<1024, 256, 0, stream>>>(h, W_id, b_id, W1, b1, W2, b2,
                                          Wp1, bp1, Wp2, deg1, deg2,
                                          agg1, agg2, w_acc, N);

    out_kernel<<<2048, 256, 0, stream>>>(h, W_id, b_id, agg1, agg2, w_acc,
                                         out, N, 1.0f / (float)N);
}

// Round 2
// 819.984 us; speedup vs baseline: 3.8451x; 3.8451x over previous
//
#include <hip/hip_runtime.h>
#include <math.h>

#define DD 64
#define HH 128

typedef __attribute__((ext_vector_type(8))) short bf16x8;
typedef __attribute__((ext_vector_type(4))) float f32x4;
typedef __attribute__((ext_vector_type(4))) int i32x4;

__device__ __forceinline__ short f2bf(float x){
    unsigned u = __builtin_bit_cast(unsigned, x);
    u += 0x7fffu + ((u >> 16) & 1u);          // RTNE
    return (short)(u >> 16);
}
__device__ __forceinline__ float bf2f(short s){
    unsigned u = ((unsigned)(unsigned short)s) << 16;
    return __builtin_bit_cast(float, u);
}
__device__ __forceinline__ float fast_tanh(float x){
    float e = __expf(2.0f * x);
    return 1.0f - 2.0f / (e + 1.0f);
}
__device__ __forceinline__ float elu1(float x){
    return x > 0.0f ? x : (__expf(x) - 1.0f);
}
__device__ __forceinline__ bf16x8 pack8(float4 a, float4 b, float s){
    bf16x8 r;
    r[0]=f2bf(a.x*s); r[1]=f2bf(a.y*s); r[2]=f2bf(a.z*s); r[3]=f2bf(a.w*s);
    r[4]=f2bf(b.x*s); r[5]=f2bf(b.y*s); r[6]=f2bf(b.z*s); r[7]=f2bf(b.w*s);
    return r;
}

__global__ __launch_bounds__(256) void deg_kernel(
    const int* __restrict__ dst1, const int* __restrict__ dst2,
    float* __restrict__ deg1, float* __restrict__ deg2, int E) {
    int e = blockIdx.x * blockDim.x + threadIdx.x;
    if (e < E) {
        atomicAdd(&deg1[dst1[e]], 1.0f);
        atomicAdd(&deg2[dst2[e]], 1.0f);
    }
}

// one wave per edge; lane = feature index. Coalesced 256B gather + 64-lane atomicAdd.
__global__ __launch_bounds__(256) void scatter_kernel(
    const float* __restrict__ h,
    const int* __restrict__ src1, const int* __restrict__ dst1,
    const int* __restrict__ src2, const int* __restrict__ dst2,
    float* __restrict__ agg1, float* __restrict__ agg2, int E) {
    int wave = blockIdx.x * 4 + (threadIdx.x >> 6);
    int lane = threadIdx.x & 63;
    if (wave < E) {
        int s = src1[wave];
        int d = dst1[wave];
        float v = h[(size_t)s * DD + lane];
        atomicAdd(&agg1[(size_t)d * DD + lane], v);
    } else if (wave < 2 * E) {
        int e = wave - E;
        int s = src2[e];
        int d = dst2[e];
        float v = h[(size_t)s * DD + lane];
        atomicAdd(&agg2[(size_t)d * DD + lane], v);
    }
}

// MFMA fused kernel: wave = 16 nodes, block = 64 nodes, persistent grid.
// GEMM1: z0 = h@W_id+b, z1 = elu(a1@W1+b1), z2 = elu(a2@W2+b2)
// GEMM2: t = z@Wp1+bp1; wsum_p += sum(tanh(t)*Wp2)
// z stored bf16 into agg row slots: agg1 row n = [z1 (128B) | z0 (128B)], agg2 row n = [z2 | unused]
__global__ __launch_bounds__(256, 2) void fuse_kernel(
    const float* __restrict__ h,
    const float* __restrict__ W_id, const float* __restrict__ b_id,
    const float* __restrict__ W1, const float* __restrict__ b1,
    const float* __restrict__ W2, const float* __restrict__ b2,
    const float* __restrict__ Wp1, const float* __restrict__ bp1,
    const float* __restrict__ Wp2,
    const float* __restrict__ deg1, const float* __restrict__ deg2,
    float* __restrict__ agg1, float* __restrict__ agg2,
    float* __restrict__ w_acc, int N)
{
    // B-fragment-order weight staging: frag(p,ct,ks) = 64 lanes x 8 bf16 contiguous
    __shared__ __align__(16) short sWb[12288];  // 3 paths * 4 ct * 2 ks * 512
    __shared__ __align__(16) short sWp[8192];   // 8 ct * 2 ks * 512
    __shared__ __align__(16) short sZ[4][3072]; // per wave: 3 paths * 2 ks * 512 (A-frag order)

    for (int i = threadIdx.x; i < 12288; i += 256) {
        int p = i >> 12, r = i & 4095;
        int ct = r >> 10, rr = r & 1023;
        int ks = rr >> 9, q = rr & 511;
        int ln = q >> 3, j = q & 7;
        int c = ct * 16 + (ln & 15);
        int k = ks * 32 + (ln >> 4) * 8 + j;
        int idx = k * DD + c;
        float v = (p == 0) ? W_id[idx] : (p == 1 ? W1[idx] : W2[idx]);
        sWb[i] = f2bf(v);
    }
    for (int i = threadIdx.x; i < 8192; i += 256) {
        int ct = i >> 10, rr = i & 1023;
        int ks = rr >> 9, q = rr & 511;
        int ln = q >> 3, j = q & 7;
        int c = ct * 16 + (ln & 15);
        int k = ks * 32 + (ln >> 4) * 8 + j;
        sWp[i] = f2bf(Wp1[k * HH + c]);
    }

    int lane = threadIdx.x & 63;
    int wv = threadIdx.x >> 6;
    int cl = lane & 15;
    int quad = lane >> 4;

    float bid[4], bb1r[4], bb2r[4];
    #pragma unroll
    for (int ct = 0; ct < 4; ct++) {
        bid[ct]  = b_id[ct*16 + cl];
        bb1r[ct] = b1[ct*16 + cl];
        bb2r[ct] = b2[ct*16 + cl];
    }
    float bpr[8], wp2r[8];
    #pragma unroll
    for (int ct = 0; ct < 8; ct++) {
        bpr[ct]  = bp1[ct*16 + cl];
        wp2r[ct] = Wp2[ct*16 + cl];
    }
    __syncthreads();

    float wsp0 = 0.f, wsp1 = 0.f, wsp2 = 0.f;
    int ntiles = (N + 63) >> 6;
    short* zw = sZ[wv];

    for (int tile = blockIdx.x; tile < ntiles; tile += gridDim.x) {
        int nb = tile * 64 + wv * 16;
        int arow = nb + cl;                        // A-frag row (node) for this lane
        int arowc = arow < N ? arow : N - 1;
        float d1 = deg1[arowc]; float inv1 = d1 > 0.f ? 1.f/d1 : 0.f;
        float d2 = deg2[arowc]; float inv2 = d2 > 0.f ? 1.f/d2 : 0.f;

        f32x4 acc[3][4];
        #pragma unroll
        for (int p = 0; p < 3; p++)
            #pragma unroll
            for (int ct = 0; ct < 4; ct++)
                acc[p][ct] = (f32x4){0.f,0.f,0.f,0.f};

        #pragma unroll
        for (int ks = 0; ks < 2; ks++) {
            int kb = ks*32 + quad*8;
            const float4* hp = (const float4*)(h    + (size_t)arowc*DD + kb);
            const float4* q1 = (const float4*)(agg1 + (size_t)arowc*DD + kb);
            const float4* q2 = (const float4*)(agg2 + (size_t)arowc*DD + kb);
            float4 hA = hp[0], hB = hp[1];
            float4 aA = q1[0], aB = q1[1];
            float4 cA = q2[0], cB = q2[1];
            bf16x8 fa0 = pack8(hA, hB, 1.0f);
            bf16x8 fa1 = pack8(aA, aB, inv1);
            bf16x8 fa2 = pack8(cA, cB, inv2);
            #pragma unroll
            for (int ct = 0; ct < 4; ct++) {
                bf16x8 w0 = *(const bf16x8*)&sWb[        (ct*2+ks)*512 + lane*8];
                bf16x8 w1 = *(const bf16x8*)&sWb[4096 +  (ct*2+ks)*512 + lane*8];
                bf16x8 w2 = *(const bf16x8*)&sWb[8192 +  (ct*2+ks)*512 + lane*8];
                acc[0][ct] = __builtin_amdgcn_mfma_f32_16x16x32_bf16(fa0, w0, acc[0][ct], 0,0,0);
                acc[1][ct] = __builtin_amdgcn_mfma_f32_16x16x32_bf16(fa1, w1, acc[1][ct], 0,0,0);
                acc[2][ct] = __builtin_amdgcn_mfma_f32_16x16x32_bf16(fa2, w2, acc[2][ct], 0,0,0);
            }
        }

        // epilogue: bias + ELU, write Z to LDS in A-fragment order
        // D elem: (m = quad*4+r, c = ct*16+cl) -> A-order offset (shorts):
        //   (c>>5)*512 + (m + ((c>>3)&3)*16)*8 + (c&7)
        #pragma unroll
        for (int ct = 0; ct < 4; ct++) {
            int c = ct*16 + cl;
            int obase = (c >> 5)*512 + ((c >> 3) & 3)*128 + (c & 7);
            #pragma unroll
            for (int r = 0; r < 4; r++) {
                int m = quad*4 + r;
                int off = obase + m*8;
                float z0 = acc[0][ct][r] + bid[ct];
                float z1 = elu1(acc[1][ct][r] + bb1r[ct]);
                float z2 = elu1(acc[2][ct][r] + bb2r[ct]);
                zw[off]        = f2bf(z0);
                zw[1024 + off] = f2bf(z1);
                zw[2048 + off] = f2bf(z2);
            }
        }

        float rmask[4];
        #pragma unroll
        for (int r = 0; r < 4; r++)
            rmask[r] = (nb + quad*4 + r) < N ? 1.f : 0.f;

        // GEMM2: t = z @ Wp1 + bp1 ; wsum += tanh(t)*Wp2 (full reduction, D-layout irrelevant)
        #pragma unroll
        for (int p = 0; p < 3; p++) {
            bf16x8 zA = *(const bf16x8*)&zw[p*1024 +       lane*8];
            bf16x8 zB = *(const bf16x8*)&zw[p*1024 + 512 + lane*8];
            float wsum = 0.f;
            #pragma unroll
            for (int ct = 0; ct < 8; ct++) {
                f32x4 t = (f32x4){0.f,0.f,0.f,0.f};
                bf16x8 u0 = *(const bf16x8*)&sWp[(ct*2+0)*512 + lane*8];
                bf16x8 u1 = *(const bf16x8*)&sWp[(ct*2+1)*512 + lane*8];
                t = __builtin_amdgcn_mfma_f32_16x16x32_bf16(zA, u0, t, 0,0,0);
                t = __builtin_amdgcn_mfma_f32_16x16x32_bf16(zB, u1, t, 0,0,0);
                float s = 0.f;
                #pragma unroll
                for (int r = 0; r < 4; r++)
                    s += fast_tanh(t[r] + bpr[ct]) * rmask[r];
                wsum += s * wp2r[ct];
            }
            if (p == 0)      wsp0 += wsum;
            else if (p == 1) wsp1 += wsum;
            else             wsp2 += wsum;
        }

        // z -> global, bf16 packed into agg row slots (rows this wave owns)
        int m8 = lane >> 3;
        int q3 = lane & 7;
        int ks2 = q3 >> 2, qq = q3 & 3;
        #pragma unroll
        for (int pass = 0; pass < 2; pass++) {
            int m = pass*8 + m8;
            int node = nb + m;
            if (node < N) {
                int lo = ks2*512 + (m + qq*16)*8;
                i32x4 v0 = *(const i32x4*)&zw[lo];
                i32x4 v1 = *(const i32x4*)&zw[1024 + lo];
                i32x4 v2 = *(const i32x4*)&zw[2048 + lo];
                char* base1 = (char*)agg1 + (size_t)node*256 + ks2*64 + qq*16;
                *(i32x4*)base1 = v1;                 // z1 in first 128B
                *(i32x4*)(base1 + 128) = v0;         // z0 in second 128B
                char* base2 = (char*)agg2 + (size_t)node*256 + ks2*64 + qq*16;
                *(i32x4*)base2 = v2;                 // z2 in first 128B
            }
        }
    }

    #pragma unroll
    for (int off = 32; off >= 1; off >>= 1) {
        wsp0 += __shfl_xor(wsp0, off, 64);
        wsp1 += __shfl_xor(wsp1, off, 64);
        wsp2 += __shfl_xor(wsp2, off, 64);
    }
    if (lane == 0) {
        atomicAdd(&w_acc[0], wsp0);
        atomicAdd(&w_acc[1], wsp1);
        atomicAdd(&w_acc[2], wsp2);
    }
}

__global__ __launch_bounds__(256) void out_kernel(
    const float* __restrict__ agg1, const float* __restrict__ agg2,
    const float* __restrict__ w_acc, float* __restrict__ out,
    int N, float invN)
{
    int tid = blockIdx.x * 256 + threadIdx.x;
    int n = tid >> 3, part = tid & 7;
    if (n >= N) return;
    float w0 = w_acc[0]*invN, w1 = w_acc[1]*invN, w2 = w_acc[2]*invN;
    float m = fmaxf(w0, fmaxf(w1, w2));
    float e0 = __expf(w0-m), e1 = __expf(w1-m), e2 = __expf(w2-m);
    float s = 1.f/(e0+e1+e2);
    float beta0 = e0*s, beta1 = e1*s, beta2 = e2*s;

    const char* r1 = (const char*)agg1 + (size_t)n*256 + part*16;
    const char* r2 = (const char*)agg2 + (size_t)n*256 + part*16;
    union U { i32x4 v; short sh[8]; };
    U z1u, z0u, z2u;
    z1u.v = *(const i32x4*)r1;
    z0u.v = *(const i32x4*)(r1 + 128);
    z2u.v = *(const i32x4*)r2;
    float tmp[8];
    #pragma unroll
    for (int j = 0; j < 8; j++)
        tmp[j] = beta0*bf2f(z0u.sh[j]) + beta1*bf2f(z1u.sh[j]) + beta2*bf2f(z2u.sh[j]);
    float4* op = (float4*)(out + (size_t)n*64 + part*8);
    op[0] = (float4){tmp[0],tmp[1],tmp[2],tmp[3]};
    op[1] = (float4){tmp[4],tmp[5],tmp[6],tmp[7]};
}

extern "C" void kernel_launch(void* const* d_in, const int* in_sizes, int n_in,
                              void* d_out, int out_size, void* d_ws, size_t ws_size,
                              hipStream_t stream) {
    const float* h    = (const float*)d_in[0];
    const int*   src1 = (const int*)d_in[1];
    const int*   dst1 = (const int*)d_in[2];
    const int*   src2 = (const int*)d_in[3];
    const int*   dst2 = (const int*)d_in[4];
    const float* W_id = (const float*)d_in[5];
    const float* b_id = (const float*)d_in[6];
    const float* W1   = (const float*)d_in[7];
    const float* b1   = (const float*)d_in[8];
    const float* W2   = (const float*)d_in[9];
    const float* b2   = (const float*)d_in[10];
    const float* Wp1  = (const float*)d_in[11];
    const float* bp1  = (const float*)d_in[12];
    const float* Wp2  = (const float*)d_in[13];
    float* out = (float*)d_out;

    int N = in_sizes[0] / DD;
    int E = in_sizes[1];

    float* ws    = (float*)d_ws;
    float* agg1  = ws;
    float* agg2  = agg1 + (size_t)N * DD;
    float* deg1  = agg2 + (size_t)N * DD;
    float* deg2  = deg1 + N;
    float* w_acc = deg2 + N;

    size_t zero_bytes = ((size_t)2 * N * DD + 2 * (size_t)N + 8) * sizeof(float);
    hipMemsetAsync(d_ws, 0, zero_bytes, stream);

    deg_kernel<<<(E + 255) / 256, 256, 0, stream>>>(dst1, dst2, deg1, deg2, E);

    int swaves = 2 * E;
    scatter_kernel<<<(swaves + 3) / 4, 256, 0, stream>>>(h, src1, dst1, src2, dst2, agg1, agg2, E);

    int ntiles = (N + 63) >> 6;
    int fblocks = ntiles < 512 ? ntiles : 512;
    fuse_kernel<<<fblocks, 256, 0, stream>>>(h, W_id, b_id, W1, b1, W2, b2,
                                             Wp1, bp1, Wp2, deg1, deg2,
                                             agg1, agg2, w_acc, N);

    out_kernel<<<(N * 8 + 255) / 256, 256, 0, stream>>>(agg1, agg2, w_acc, out, N, 1.0f / (float)N);
}